// Round 6
// baseline (175.171 us; speedup 1.0000x reference)
//
#include <hip/hip_runtime.h>
#include <hip/hip_bf16.h>

// ImmuneMemoryModule — MI355X pipeline v6 (counted-vmcnt ring pipeline).
// prep_ff: pack W1 (+b1 as k-slot 20) / W2 / memory into kappa-permuted
//          lane-contiguous fragment layouts; ff[.,20]=1.0 so GEMM2 adds b1.
// mega:    4 waves/block, 32 rows/wave, grid 512 (2 blocks/CU). One unified
//          96-step slab stream (32x8KB W2, 64x8KB Mp) through a 3-buffer LDS
//          ring, staged 2 ahead via global_load_lds. Per step:
//            s_waitcnt vmcnt(2)  (slab t landed; t+1 stays in flight)
//            raw s_barrier       (no vmcnt(0)/lgkmcnt(0) drain!)
//            stage slab t+2      (into buffer of t-1, reads provably done)
//            ds_read + MFMA
//          h/q stay in registers (kappa slot relabeling); 1/|q| applied to the
//          final max only; gather rows are exact fp32.

typedef __attribute__((ext_vector_type(8))) short short8;
typedef __attribute__((ext_vector_type(4))) float f32x4;

#define MFMA(a, b, c) __builtin_amdgcn_mfma_f32_16x16x32_bf16((a), (b), (c), 0, 0, 0)

static __device__ __forceinline__ short bfb(float f) {
  return (short)__builtin_bit_cast(unsigned short, __float2bfloat16(f));
}
static __device__ __forceinline__ unsigned short bf16bits(float f) {
  return __builtin_bit_cast(unsigned short, __float2bfloat16(f));
}
static __device__ __forceinline__ float sel10(const float a[10], int i) {
  float v = a[0];
#pragma unroll
  for (int j = 1; j < 10; ++j) v = (i == j) ? a[j] : v;
  return v;
}

typedef const __attribute__((address_space(1))) unsigned int* gas_p;
typedef __attribute__((address_space(3))) unsigned int* las_p;
static __device__ __forceinline__ void async16(const void* g, void* l) {
  __builtin_amdgcn_global_load_lds((gas_p)g, (las_p)l, 16, 0, 0);
}

// ---------------------------------------------------------------------------
// prep_ff
// kappa(kt,g,j) = 32*kt + 16*(j>>2) + 4*g + (j&3)
// W1p [32 ct][64 lane][8 j]: k=8g+j: k<20 -> W1[k][col]; k==20 -> b1[col]; else 0
// W2p [16 kt][16 c][64 lane][8 j] = W2[kappa][c*16+jj]
// Mp  [16 cch][4 nl][8 kt][64 lane][8 j] = mhat[(cch*4+nl)*16+jj][kappa]
// ff  [B][32] bf16: k<10 sin(xp[k]), 10..19 cos(xp[k-10]), k==20 -> 1.0, else 0
// ---------------------------------------------------------------------------
__global__ __launch_bounds__(256) void prep_ff_kernel(
    const float* __restrict__ W1, const float* __restrict__ b1,
    const float* __restrict__ W2, const float* __restrict__ mem,
    const float* __restrict__ query, const float* __restrict__ Bmat,
    __hip_bfloat16* __restrict__ W1p, __hip_bfloat16* __restrict__ W2p,
    __hip_bfloat16* __restrict__ Mp, __hip_bfloat16* __restrict__ ff) {
  __shared__ __align__(16) float Bl[10 * 512];  // ff: [f][d] 20KB; prep: invl
  const int b = blockIdx.x, tid = threadIdx.x;
  if (b < 16) {
    float* invl = Bl;  // [64]
    const int w = tid >> 6, lane = tid & 63, g = lane >> 4, jj = lane & 15;
    {
      int r = w * 16 + jj;  // 0..63 local row
      const float4* m4 = (const float4*)(mem + (size_t)(b * 64 + r) * 256);
      float ss = 0.f;
      for (int t = 0; t < 16; ++t) {
        float4 v = m4[g * 16 + t];
        ss += v.x * v.x + v.y * v.y + v.z * v.z + v.w * v.w;
      }
      ss += __shfl_xor(ss, 16);
      ss += __shfl_xor(ss, 32);
      if (g == 0) invl[r] = rsqrtf(fmaxf(ss, 1e-30f));
    }
    __syncthreads();
    for (int u = 0; u < 64; ++u) {
      int t = u * 256 + tid;  // 0..16383 within this chunk
      int j = t & 7, lane2 = (t >> 3) & 63, kt = (t >> 9) & 7, nl = t >> 12;
      int g2 = lane2 >> 4, jp = lane2 & 15;
      int nloc = nl * 16 + jp;
      int kap = 32 * kt + 16 * (j >> 2) + 4 * g2 + (j & 3);
      float v = mem[(size_t)(b * 64 + nloc) * 256 + kap] * invl[nloc];
      Mp[(size_t)b * 16384 + t] = __float2bfloat16(v);
    }
  } else if (b == 16) {
    for (int idx = tid; idx < 16384; idx += 256) {
      int j = idx & 7, lane2 = (idx >> 3) & 63, ct = idx >> 9;
      int g2 = lane2 >> 4, jp = lane2 & 15;
      int k = 8 * g2 + j;
      float v = 0.f;
      if (k < 20) v = W1[k * 512 + ct * 16 + jp];
      else if (k == 20) v = b1[ct * 16 + jp];
      W1p[idx] = __float2bfloat16(v);
    }
  } else if (b < 33) {  // b = 17..32 -> W2p (131072 elems)
    int bb = b - 17;
    for (int u = 0; u < 32; ++u) {
      int idx = bb * 8192 + u * 256 + tid;
      int j = idx & 7, lane2 = (idx >> 3) & 63, c = (idx >> 9) & 15, kt = idx >> 13;
      int g2 = lane2 >> 4, jp = lane2 & 15;
      int kap = 32 * kt + 16 * (j >> 2) + 4 * g2 + (j & 3);
      W2p[idx] = __float2bfloat16(W2[(size_t)kap * 256 + c * 16 + jp]);
    }
  } else {
    // ---- ff: 32 rows/block, 2 rows per 16-lane group ----
    const int bb = b - 33;
    for (int i = tid; i < 5120; i += 256) {
      int d = i / 10, f = i - d * 10;
      Bl[f * 512 + d] = Bmat[i];  // B_mat row-major [512][10]
    }
    __syncthreads();
    const int wv = tid >> 6, lane = tid & 63;
    const int g = lane >> 4, jj = lane & 15;
    const long r0 = (long)bb * 32 + (wv * 4 + g) * 2;
    const float4* qa = (const float4*)(query + r0 * 512);
    const float4* qb = (const float4*)(query + (r0 + 1) * 512);

    float acc[2][10];
#pragma unroll
    for (int f = 0; f < 10; ++f) { acc[0][f] = 0.f; acc[1][f] = 0.f; }
#pragma unroll
    for (int k = 0; k < 8; ++k) {
      float4 va = qa[jj + 16 * k];
      float4 vb = qb[jj + 16 * k];
#pragma unroll
      for (int f = 0; f < 10; ++f) {
        float4 bv = *(const float4*)(Bl + f * 512 + 4 * (jj + 16 * k));
        acc[0][f] = fmaf(va.x, bv.x, fmaf(va.y, bv.y, fmaf(va.z, bv.z, fmaf(va.w, bv.w, acc[0][f]))));
        acc[1][f] = fmaf(vb.x, bv.x, fmaf(vb.y, bv.y, fmaf(vb.z, bv.z, fmaf(vb.w, bv.w, acc[1][f]))));
      }
    }
#pragma unroll
    for (int r = 0; r < 2; ++r) {
#pragma unroll
      for (int f = 0; f < 10; ++f) {
        float s = acc[r][f];
        s += __shfl_xor(s, 1); s += __shfl_xor(s, 2);
        s += __shfl_xor(s, 4); s += __shfl_xor(s, 8);
        acc[r][f] = s;
      }
      int base = (jj < 5) ? 2 * jj : 2 * jj - 10;
      float a0 = sel10(acc[r], base);
      float a1 = sel10(acc[r], base + 1);
      float v0 = 0.f, v1 = 0.f;
      if (jj < 5) { v0 = sinf(a0); v1 = sinf(a1); }
      else if (jj < 10) { v0 = cosf(a0); v1 = cosf(a1); }
      else if (jj == 10) { v0 = 1.0f; }  // k=20 constant-one -> +b1 via W1p
      ushort2 pk;
      pk.x = bf16bits(v0);
      pk.y = bf16bits(v1);
      ((ushort2*)ff)[(r0 + r) * 16 + jj] = pk;
    }
  }
}

// ---------------------------------------------------------------------------
// mega: 256 threads (4 waves), 32 rows/wave, grid 512 -> 2 blocks/CU.
// LDS 58368 B: [0,32K) W1p static, [32K,33K) b2, [33K, 33K+24K) ring 3x8KB.
// Slab stream: s<32 -> W2p slab s (kt=s>>1, c-half=s&1); s>=32 -> Mp chunk s-32.
// ---------------------------------------------------------------------------
#define STAGE_SLAB(s)                                                       \
  do {                                                                      \
    const char* s_ = ((s) < 32 ? (const char*)W2p + (size_t)(s) * 8192      \
                               : (const char*)Mp + (size_t)((s) - 32) * 8192); \
    char* d_ = lds + 33792 + ((s) % 3) * 8192;                              \
    async16(s_ + tid * 16, d_ + tid * 16);                                  \
    async16(s_ + 4096 + tid * 16, d_ + 4096 + tid * 16);                    \
  } while (0)

__global__ __launch_bounds__(256, 2) void mega_kernel(
    const __hip_bfloat16* __restrict__ ff, const __hip_bfloat16* __restrict__ W1p,
    const __hip_bfloat16* __restrict__ W2p, const float* __restrict__ b2,
    const __hip_bfloat16* __restrict__ Mp, const float* __restrict__ mem,
    float* __restrict__ out) {
  __shared__ __align__(16) char lds[58368];
  const int tid = threadIdx.x, w = tid >> 6, lane = tid & 63;
  const int g = lane >> 4, jj = lane & 15;
  const int rowBase = blockIdx.x * 128 + w * 32;
  const f32x4 z4 = {0.f, 0.f, 0.f, 0.f};

  // ---- prologue ----
  // ffq loads first, then b2->LDS (its dependent ds_write makes the compiler
  // drain vmcnt(0) here, retiring ffq too), then all staging.
  short8 ffq0 = *(const short8*)(ff + (size_t)(rowBase + jj) * 32 + g * 8);
  short8 ffq1 = *(const short8*)(ff + (size_t)(rowBase + 16 + jj) * 32 + g * 8);
  {
    float v = b2[tid];
    *(float*)(lds + 32768 + tid * 4) = v;  // compiler: vmcnt(0) before ds_write
  }
#pragma unroll
  for (int r = 0; r < 8; ++r)  // W1p 32KB -> LDS[0,32K)
    async16((const char*)W1p + r * 4096 + tid * 16, lds + r * 4096 + tid * 16);
  STAGE_SLAB(0);
  STAGE_SLAB(1);

  f32x4 acc3[2][16];
#pragma unroll
  for (int c = 0; c < 16; ++c) { acc3[0][c] = z4; acc3[1][c] = z4; }
  short8 hf0, hf1;
  short8 qfrag[2][8];
  float invqn[2];
  float runmax[2][4];
  int runidx[2][4];
#pragma unroll
  for (int rt = 0; rt < 2; ++rt)
#pragma unroll
    for (int i = 0; i < 4; ++i) { runmax[rt][i] = -1e30f; runidx[rt][i] = 0; }

  // ---- 96-step counted-vmcnt ring pipeline ----
  for (int t = 0; t < 96; ++t) {
    if (t < 95) {
      asm volatile("s_waitcnt vmcnt(2)" ::: "memory");  // slab t landed (own)
    } else {
      asm volatile("s_waitcnt vmcnt(0)" ::: "memory");
    }
    __builtin_amdgcn_s_barrier();                       // all waves: slab t ready
    asm volatile("" ::: "memory");
    __builtin_amdgcn_sched_barrier(0);
    if (t + 2 < 96) STAGE_SLAB(t + 2);                  // buffer of t-1: reads done
    const char* buf = lds + 33792 + (t % 3) * 8192;

    if (t < 32) {
      // ---- GEMM2 (even steps) + GEMM3 ----
      const int kt = t >> 1;
      if ((t & 1) == 0) {
        short8 a0 = *(const short8*)(lds + (2 * kt) * 1024 + lane * 16);
        short8 a1 = *(const short8*)(lds + (2 * kt + 1) * 1024 + lane * 16);
        f32x4 d00 = MFMA(a0, ffq0, z4);
        f32x4 d01 = MFMA(a1, ffq0, z4);
        f32x4 d10 = MFMA(a0, ffq1, z4);
        f32x4 d11 = MFMA(a1, ffq1, z4);
#pragma unroll
        for (int i = 0; i < 4; ++i) {
          hf0[i] = bfb(d00[i] > 0.f ? d00[i] : 0.f);
          hf0[4 + i] = bfb(d01[i] > 0.f ? d01[i] : 0.f);
          hf1[i] = bfb(d10[i] > 0.f ? d10[i] : 0.f);
          hf1[4 + i] = bfb(d11[i] > 0.f ? d11[i] : 0.f);
        }
#pragma unroll
        for (int c = 0; c < 8; ++c) {
          short8 bfr = *(const short8*)(buf + c * 1024 + lane * 16);
          acc3[0][c] = MFMA(bfr, hf0, acc3[0][c]);
          acc3[1][c] = MFMA(bfr, hf1, acc3[1][c]);
        }
      } else {
#pragma unroll
        for (int c = 0; c < 8; ++c) {
          short8 bfr = *(const short8*)(buf + c * 1024 + lane * 16);
          acc3[0][8 + c] = MFMA(bfr, hf0, acc3[0][8 + c]);
          acc3[1][8 + c] = MFMA(bfr, hf1, acc3[1][8 + c]);
        }
      }
      if (t == 31) {
        // ---- q epilogue: +b2 (LDS), |q|^2, pack bf16 qfrag ----
        const float* b2l = (const float*)(lds + 32768);
#pragma unroll
        for (int rt = 0; rt < 2; ++rt) {
          float qn = 0.f;
#pragma unroll
          for (int c = 0; c < 16; ++c) {
            f32x4 bb = *(const f32x4*)(b2l + c * 16 + 4 * g);
#pragma unroll
            for (int i = 0; i < 4; ++i) {
              float v = (rt ? acc3[1][c][i] : acc3[0][c][i]) + bb[i];
              qn += v * v;
              qfrag[rt][c >> 1][(c & 1) * 4 + i] = bfb(v);
            }
          }
          qn += __shfl_xor(qn, 16);
          qn += __shfl_xor(qn, 32);
          invqn[rt] = rsqrtf(fmaxf(qn, 1e-30f));
        }
      }
    } else {
      // ---- GEMM4: one 16-n chunk ----
      f32x4 a40 = z4, a41 = z4;
#pragma unroll
      for (int kt = 0; kt < 8; ++kt) {
        short8 bfr = *(const short8*)(buf + kt * 1024 + lane * 16);
        a40 = MFMA(qfrag[0][kt], bfr, a40);
        a41 = MFMA(qfrag[1][kt], bfr, a41);
      }
      const int n = (t - 32) * 16 + jj;
#pragma unroll
      for (int i = 0; i < 4; ++i) {
        if (a40[i] > runmax[0][i]) { runmax[0][i] = a40[i]; runidx[0][i] = n; }
        if (a41[i] > runmax[1][i]) { runmax[1][i] = a41[i]; runidx[1][i] = n; }
      }
    }
  }

  // ---- reduce across jj-lanes (first-max tie-break), threshold, write ----
  const float4* mem4 = (const float4*)mem;
  float4* out4 = (float4*)out;
#pragma unroll
  for (int rt = 0; rt < 2; ++rt) {
#pragma unroll
    for (int i = 0; i < 4; ++i) {
#pragma unroll
      for (int o = 1; o < 16; o <<= 1) {
        float v2 = __shfl_xor(runmax[rt][i], o);
        int i2 = __shfl_xor(runidx[rt][i], o);
        if (v2 > runmax[rt][i] || (v2 == runmax[rt][i] && i2 < runidx[rt][i])) {
          runmax[rt][i] = v2;
          runidx[rt][i] = i2;
        }
      }
    }
#pragma unroll
    for (int i = 0; i < 4; ++i) {
      float iq = __shfl(invqn[rt], 4 * g + i, 64);  // lane (g'=0, jj=4g+i)
      float ms = runmax[rt][i] * iq;
      int s = (ms < 0.7f) ? -1 : runidx[rt][i];
      size_t row = (size_t)rowBase + rt * 16 + 4 * g + i;
#pragma unroll
      for (int cq = 0; cq < 4; ++cq) {
        int col = cq * 16 + jj;
        float4 v = {0.f, 0.f, 0.f, 0.f};
        if (s >= 0) v = mem4[(size_t)s * 64 + col];
        out4[row * 64 + col] = v;
      }
    }
  }
}

extern "C" void kernel_launch(void* const* d_in, const int* in_sizes, int n_in,
                              void* d_out, int out_size, void* d_ws, size_t ws_size,
                              hipStream_t stream) {
  const float* query = (const float*)d_in[0];
  const float* Bmat = (const float*)d_in[1];
  const float* W1 = (const float*)d_in[2];
  const float* b1 = (const float*)d_in[3];
  const float* W2 = (const float*)d_in[4];
  const float* b2 = (const float*)d_in[5];
  const float* mem = (const float*)d_in[6];
  float* out = (float*)d_out;

  char* ws = (char*)d_ws;
  __hip_bfloat16* ff = (__hip_bfloat16*)ws;                        // 4 MB
  __hip_bfloat16* Mp = (__hip_bfloat16*)(ws + 4194304);            // 512 KB
  __hip_bfloat16* W2p = (__hip_bfloat16*)(ws + 4194304 + 524288);  // 256 KB
  __hip_bfloat16* W1p = (__hip_bfloat16*)(ws + 4194304 + 786432);  // 32 KB

  prep_ff_kernel<<<dim3(2081), dim3(256), 0, stream>>>(W1, b1, W2, mem, query,
                                                       Bmat, W1p, W2p, Mp, ff);
  mega_kernel<<<dim3(512), dim3(256), 0, stream>>>(ff, W1p, W2p, b2, Mp, mem, out);
}

// Round 7
// 94.621 us; speedup vs baseline: 1.8513x; 1.8513x over previous
//
#include <hip/hip_runtime.h>
#include <hip/hip_bf16.h>

// ImmuneMemoryModule — MI355X pipeline v7 (counted-vmcnt ring, spill-free).
// prep_ff: pack W1 (+b1 as k-slot 20) / W2 / memory into kappa-permuted
//          lane-contiguous fragment layouts; ff[.,20]=1.0 so GEMM2 adds b1.
// mega:    4 waves/block, 32 rows/wave, grid 512 (2 blocks/CU). 96 slab steps
//          (32x8KB W2, 64x8KB Mp) through a 4-buffer LDS ring staged 3 ahead
//          via global_load_lds. Per step:
//            s_waitcnt vmcnt(4)   (slab t landed; t+1,t+2 in flight)
//            s_barrier            (never vmcnt(0) in the main loops)
//            stage slab t+3       (into buffer read at t-1: provably done)
//            ds_read + MFMA
//          Two separate loops (GEMM2/3 then GEMM4) + 4-step-unrolled bodies so
//          all ring indices are compile-time constants -> no scratch spills
//          (v6 failure mode: 1 merged loop + runtime %3 -> VGPR 128 + 233MB
//          scratch traffic). h/q stay in registers; 1/|q| on final max only.

typedef __attribute__((ext_vector_type(8))) short short8;
typedef __attribute__((ext_vector_type(4))) float f32x4;

#define MFMA(a, b, c) __builtin_amdgcn_mfma_f32_16x16x32_bf16((a), (b), (c), 0, 0, 0)

static __device__ __forceinline__ short bfb(float f) {
  return (short)__builtin_bit_cast(unsigned short, __float2bfloat16(f));
}
static __device__ __forceinline__ unsigned short bf16bits(float f) {
  return __builtin_bit_cast(unsigned short, __float2bfloat16(f));
}
static __device__ __forceinline__ float sel10(const float a[10], int i) {
  float v = a[0];
#pragma unroll
  for (int j = 1; j < 10; ++j) v = (i == j) ? a[j] : v;
  return v;
}

typedef const __attribute__((address_space(1))) unsigned int* gas_p;
typedef __attribute__((address_space(3))) unsigned int* las_p;
static __device__ __forceinline__ void async16(const void* g, void* l) {
  __builtin_amdgcn_global_load_lds((gas_p)g, (las_p)l, 16, 0, 0);
}

// ---------------------------------------------------------------------------
// prep_ff (unchanged from v6 — validated)
// kappa(kt,g,j) = 32*kt + 16*(j>>2) + 4*g + (j&3)
// W1p [32 ct][64 lane][8 j]: k=8g+j: k<20 -> W1[k][col]; k==20 -> b1[col]; else 0
// W2p [16 kt][16 c][64 lane][8 j] = W2[kappa][c*16+jj]
// Mp  [16 cch][4 nl][8 kt][64 lane][8 j] = mhat[(cch*4+nl)*16+jj][kappa]
// ff  [B][32] bf16: k<10 sin(xp[k]), 10..19 cos(xp[k-10]), k==20 -> 1.0, else 0
// ---------------------------------------------------------------------------
__global__ __launch_bounds__(256) void prep_ff_kernel(
    const float* __restrict__ W1, const float* __restrict__ b1,
    const float* __restrict__ W2, const float* __restrict__ mem,
    const float* __restrict__ query, const float* __restrict__ Bmat,
    __hip_bfloat16* __restrict__ W1p, __hip_bfloat16* __restrict__ W2p,
    __hip_bfloat16* __restrict__ Mp, __hip_bfloat16* __restrict__ ff) {
  __shared__ __align__(16) float Bl[10 * 512];  // ff: [f][d] 20KB; prep: invl
  const int b = blockIdx.x, tid = threadIdx.x;
  if (b < 16) {
    float* invl = Bl;  // [64]
    const int w = tid >> 6, lane = tid & 63, g = lane >> 4, jj = lane & 15;
    {
      int r = w * 16 + jj;  // 0..63 local row
      const float4* m4 = (const float4*)(mem + (size_t)(b * 64 + r) * 256);
      float ss = 0.f;
      for (int t = 0; t < 16; ++t) {
        float4 v = m4[g * 16 + t];
        ss += v.x * v.x + v.y * v.y + v.z * v.z + v.w * v.w;
      }
      ss += __shfl_xor(ss, 16);
      ss += __shfl_xor(ss, 32);
      if (g == 0) invl[r] = rsqrtf(fmaxf(ss, 1e-30f));
    }
    __syncthreads();
    for (int u = 0; u < 64; ++u) {
      int t = u * 256 + tid;  // 0..16383 within this chunk
      int j = t & 7, lane2 = (t >> 3) & 63, kt = (t >> 9) & 7, nl = t >> 12;
      int g2 = lane2 >> 4, jp = lane2 & 15;
      int nloc = nl * 16 + jp;
      int kap = 32 * kt + 16 * (j >> 2) + 4 * g2 + (j & 3);
      float v = mem[(size_t)(b * 64 + nloc) * 256 + kap] * invl[nloc];
      Mp[(size_t)b * 16384 + t] = __float2bfloat16(v);
    }
  } else if (b == 16) {
    for (int idx = tid; idx < 16384; idx += 256) {
      int j = idx & 7, lane2 = (idx >> 3) & 63, ct = idx >> 9;
      int g2 = lane2 >> 4, jp = lane2 & 15;
      int k = 8 * g2 + j;
      float v = 0.f;
      if (k < 20) v = W1[k * 512 + ct * 16 + jp];
      else if (k == 20) v = b1[ct * 16 + jp];
      W1p[idx] = __float2bfloat16(v);
    }
  } else if (b < 33) {  // b = 17..32 -> W2p (131072 elems)
    int bb = b - 17;
    for (int u = 0; u < 32; ++u) {
      int idx = bb * 8192 + u * 256 + tid;
      int j = idx & 7, lane2 = (idx >> 3) & 63, c = (idx >> 9) & 15, kt = idx >> 13;
      int g2 = lane2 >> 4, jp = lane2 & 15;
      int kap = 32 * kt + 16 * (j >> 2) + 4 * g2 + (j & 3);
      W2p[idx] = __float2bfloat16(W2[(size_t)kap * 256 + c * 16 + jp]);
    }
  } else {
    // ---- ff: 32 rows/block, 2 rows per 16-lane group ----
    const int bb = b - 33;
    for (int i = tid; i < 5120; i += 256) {
      int d = i / 10, f = i - d * 10;
      Bl[f * 512 + d] = Bmat[i];  // B_mat row-major [512][10]
    }
    __syncthreads();
    const int wv = tid >> 6, lane = tid & 63;
    const int g = lane >> 4, jj = lane & 15;
    const long r0 = (long)bb * 32 + (wv * 4 + g) * 2;
    const float4* qa = (const float4*)(query + r0 * 512);
    const float4* qb = (const float4*)(query + (r0 + 1) * 512);

    float acc[2][10];
#pragma unroll
    for (int f = 0; f < 10; ++f) { acc[0][f] = 0.f; acc[1][f] = 0.f; }
#pragma unroll
    for (int k = 0; k < 8; ++k) {
      float4 va = qa[jj + 16 * k];
      float4 vb = qb[jj + 16 * k];
#pragma unroll
      for (int f = 0; f < 10; ++f) {
        float4 bv = *(const float4*)(Bl + f * 512 + 4 * (jj + 16 * k));
        acc[0][f] = fmaf(va.x, bv.x, fmaf(va.y, bv.y, fmaf(va.z, bv.z, fmaf(va.w, bv.w, acc[0][f]))));
        acc[1][f] = fmaf(vb.x, bv.x, fmaf(vb.y, bv.y, fmaf(vb.z, bv.z, fmaf(vb.w, bv.w, acc[1][f]))));
      }
    }
#pragma unroll
    for (int r = 0; r < 2; ++r) {
#pragma unroll
      for (int f = 0; f < 10; ++f) {
        float s = acc[r][f];
        s += __shfl_xor(s, 1); s += __shfl_xor(s, 2);
        s += __shfl_xor(s, 4); s += __shfl_xor(s, 8);
        acc[r][f] = s;
      }
      int base = (jj < 5) ? 2 * jj : 2 * jj - 10;
      float a0 = sel10(acc[r], base);
      float a1 = sel10(acc[r], base + 1);
      float v0 = 0.f, v1 = 0.f;
      if (jj < 5) { v0 = sinf(a0); v1 = sinf(a1); }
      else if (jj < 10) { v0 = cosf(a0); v1 = cosf(a1); }
      else if (jj == 10) { v0 = 1.0f; }  // k=20 constant-one -> +b1 via W1p
      ushort2 pk;
      pk.x = bf16bits(v0);
      pk.y = bf16bits(v1);
      ((ushort2*)ff)[(r0 + r) * 16 + jj] = pk;
    }
  }
}

// ---------------------------------------------------------------------------
// mega: 256 threads (4 waves), 32 rows/wave, grid 512 -> 2 blocks/CU.
// LDS 66560 B: [0,32K) W1p, [32K,33K) b2, [33K,65K) ring 4x8KB.
// Slab s: s<32 -> W2p (kt=s>>1, c-half=s&1); s>=32 -> Mp nl-group s-32.
// ---------------------------------------------------------------------------
#define WAITV(N) asm volatile("s_waitcnt vmcnt(" #N ")" ::: "memory")
#define BAR()                        \
  do {                               \
    __builtin_amdgcn_s_barrier();    \
    asm volatile("" ::: "memory");   \
  } while (0)

#define STAGE_SLAB(s, bi)                                                       \
  do {                                                                          \
    const char* sp_ = ((s) < 32) ? (const char*)W2p + (size_t)(s) * 8192        \
                                 : (const char*)Mp + ((size_t)(s) - 32) * 8192; \
    char* dp_ = lds + 33792 + (bi) * 8192;                                      \
    async16(sp_ + tid * 16, dp_ + tid * 16);                                    \
    async16(sp_ + 4096 + tid * 16, dp_ + 4096 + tid * 16);                      \
  } while (0)

// even W2 step t: build h-slice (W1 from LDS) + first 8 c's of this kt
#define G3_EVEN(t, bi)                                                          \
  do {                                                                          \
    const char* buf = lds + 33792 + (bi) * 8192;                                \
    short8 a0 = *(const short8*)(lds + (size_t)(t) * 1024 + lane * 16);         \
    short8 a1 = *(const short8*)(lds + (size_t)((t) + 1) * 1024 + lane * 16);   \
    f32x4 d00 = MFMA(a0, ffq0, z4);                                             \
    f32x4 d01 = MFMA(a1, ffq0, z4);                                             \
    f32x4 d10 = MFMA(a0, ffq1, z4);                                             \
    f32x4 d11 = MFMA(a1, ffq1, z4);                                             \
    _Pragma("unroll") for (int i = 0; i < 4; ++i) {                             \
      hf0[i] = bfb(d00[i] > 0.f ? d00[i] : 0.f);                                \
      hf0[4 + i] = bfb(d01[i] > 0.f ? d01[i] : 0.f);                            \
      hf1[i] = bfb(d10[i] > 0.f ? d10[i] : 0.f);                                \
      hf1[4 + i] = bfb(d11[i] > 0.f ? d11[i] : 0.f);                            \
    }                                                                           \
    _Pragma("unroll") for (int c = 0; c < 8; ++c) {                             \
      short8 bfr = *(const short8*)(buf + c * 1024 + lane * 16);                \
      acc3a[c] = MFMA(bfr, hf0, acc3a[c]);                                      \
      acc3b[c] = MFMA(bfr, hf1, acc3b[c]);                                      \
    }                                                                           \
  } while (0)

// odd W2 step: second 8 c's of same kt (reuses hf0/hf1)
#define G3_ODD(bi)                                                              \
  do {                                                                          \
    const char* buf = lds + 33792 + (bi) * 8192;                                \
    _Pragma("unroll") for (int c = 0; c < 8; ++c) {                             \
      short8 bfr = *(const short8*)(buf + c * 1024 + lane * 16);                \
      acc3a[8 + c] = MFMA(bfr, hf0, acc3a[8 + c]);                              \
      acc3b[8 + c] = MFMA(bfr, hf1, acc3b[8 + c]);                              \
    }                                                                           \
  } while (0)

// Mp step t (t in [32,96)): one 16-n group, running max/argmax
#define G4(t, bi)                                                               \
  do {                                                                          \
    const char* buf = lds + 33792 + (bi) * 8192;                                \
    f32x4 a40 = z4, a41 = z4;                                                   \
    _Pragma("unroll") for (int kt = 0; kt < 8; ++kt) {                          \
      short8 bfr = *(const short8*)(buf + kt * 1024 + lane * 16);               \
      a40 = MFMA(qfrag0[kt], bfr, a40);                                         \
      a41 = MFMA(qfrag1[kt], bfr, a41);                                         \
    }                                                                           \
    const int n_ = ((t) - 32) * 16 + jj;                                        \
    _Pragma("unroll") for (int i = 0; i < 4; ++i) {                             \
      if (a40[i] > runmax0[i]) { runmax0[i] = a40[i]; runidx0[i] = n_; }        \
      if (a41[i] > runmax1[i]) { runmax1[i] = a41[i]; runidx1[i] = n_; }        \
    }                                                                           \
  } while (0)

__global__ __launch_bounds__(256, 2) void mega_kernel(
    const __hip_bfloat16* __restrict__ ff, const __hip_bfloat16* __restrict__ W1p,
    const __hip_bfloat16* __restrict__ W2p, const float* __restrict__ b2,
    const __hip_bfloat16* __restrict__ Mp, const float* __restrict__ mem,
    float* __restrict__ out) {
  __shared__ __align__(16) char lds[66560];
  const int tid = threadIdx.x, w = tid >> 6, lane = tid & 63;
  const int g = lane >> 4, jj = lane & 15;
  const int rowBase = blockIdx.x * 128 + w * 32;
  const f32x4 z4 = {0.f, 0.f, 0.f, 0.f};

  // ---- prologue ----
  short8 ffq0 = *(const short8*)(ff + (size_t)(rowBase + jj) * 32 + g * 8);
  short8 ffq1 = *(const short8*)(ff + (size_t)(rowBase + 16 + jj) * 32 + g * 8);
  {
    float v = b2[tid];
    *(float*)(lds + 32768 + tid * 4) = v;  // compiler: vmcnt(0) before ds_write
  }
#pragma unroll
  for (int r = 0; r < 8; ++r)  // W1p 32KB -> LDS[0,32K)  (8 oldest loads)
    async16((const char*)W1p + r * 4096 + tid * 16, lds + r * 4096 + tid * 16);
  STAGE_SLAB(0, 0);
  STAGE_SLAB(1, 1);
  STAGE_SLAB(2, 2);

  // ---- loop 1: GEMM2+3 (t = 0..31) ----
  f32x4 acc3a[16], acc3b[16];
#pragma unroll
  for (int c = 0; c < 16; ++c) { acc3a[c] = z4; acc3b[c] = z4; }
  short8 hf0, hf1;

  for (int it = 0; it < 8; ++it) {
    const int t0 = it * 4;
    WAITV(4); BAR(); STAGE_SLAB(t0 + 3, 3); G3_EVEN(t0, 0);
    WAITV(4); BAR(); STAGE_SLAB(t0 + 4, 0); G3_ODD(1);
    WAITV(4); BAR(); STAGE_SLAB(t0 + 5, 1); G3_EVEN(t0 + 2, 2);
    WAITV(4); BAR(); STAGE_SLAB(t0 + 6, 2); G3_ODD(3);
  }

  // ---- q epilogue: +b2 (LDS), |q|^2, pack bf16 qfrag ----
  short8 qfrag0[8], qfrag1[8];
  float invqn0, invqn1;
  {
    const float* b2l = (const float*)(lds + 32768);
    float qn0 = 0.f, qn1 = 0.f;
#pragma unroll
    for (int c = 0; c < 16; ++c) {
      f32x4 bb = *(const f32x4*)(b2l + c * 16 + 4 * g);
#pragma unroll
      for (int i = 0; i < 4; ++i) {
        float v0 = acc3a[c][i] + bb[i];
        float v1 = acc3b[c][i] + bb[i];
        qn0 += v0 * v0;
        qn1 += v1 * v1;
        qfrag0[c >> 1][(c & 1) * 4 + i] = bfb(v0);
        qfrag1[c >> 1][(c & 1) * 4 + i] = bfb(v1);
      }
    }
    qn0 += __shfl_xor(qn0, 16); qn0 += __shfl_xor(qn0, 32);
    qn1 += __shfl_xor(qn1, 16); qn1 += __shfl_xor(qn1, 32);
    invqn0 = rsqrtf(fmaxf(qn0, 1e-30f));
    invqn1 = rsqrtf(fmaxf(qn1, 1e-30f));
  }

  // ---- loop 2: GEMM4 (t = 32..95), peeled tail ----
  float runmax0[4], runmax1[4];
  int runidx0[4], runidx1[4];
#pragma unroll
  for (int i = 0; i < 4; ++i) {
    runmax0[i] = -1e30f; runidx0[i] = 0;
    runmax1[i] = -1e30f; runidx1[i] = 0;
  }

  for (int it = 0; it < 15; ++it) {
    const int t0 = 32 + it * 4;
    WAITV(4); BAR(); STAGE_SLAB(t0 + 3, 3); G4(t0, 0);
    WAITV(4); BAR(); STAGE_SLAB(t0 + 4, 0); G4(t0 + 1, 1);
    WAITV(4); BAR(); STAGE_SLAB(t0 + 5, 1); G4(t0 + 2, 2);
    WAITV(4); BAR(); STAGE_SLAB(t0 + 6, 2); G4(t0 + 3, 3);
  }
  // t = 92..95 (slab 95 staged at t=92; waits 4/4/2/0)
  WAITV(4); BAR(); STAGE_SLAB(95, 3); G4(92, 0);
  WAITV(4); BAR(); G4(93, 1);
  WAITV(2); BAR(); G4(94, 2);
  WAITV(0); BAR(); G4(95, 3);

  // ---- reduce across jj-lanes (first-max tie-break), threshold, write ----
  const float4* mem4 = (const float4*)mem;
  float4* out4 = (float4*)out;
#pragma unroll
  for (int rt = 0; rt < 2; ++rt) {
    float* rmax = rt ? runmax1 : runmax0;
    int* ridx = rt ? runidx1 : runidx0;
    float iqv = rt ? invqn1 : invqn0;
#pragma unroll
    for (int i = 0; i < 4; ++i) {
#pragma unroll
      for (int o = 1; o < 16; o <<= 1) {
        float v2 = __shfl_xor(rmax[i], o);
        int i2 = __shfl_xor(ridx[i], o);
        if (v2 > rmax[i] || (v2 == rmax[i] && i2 < ridx[i])) {
          rmax[i] = v2;
          ridx[i] = i2;
        }
      }
    }
#pragma unroll
    for (int i = 0; i < 4; ++i) {
      float iq = __shfl(iqv, 4 * g + i, 64);  // lane (g'=0, jj=4g+i)
      float ms = rmax[i] * iq;
      int s = (ms < 0.7f) ? -1 : ridx[i];
      size_t row = (size_t)rowBase + rt * 16 + 4 * g + i;
#pragma unroll
      for (int cq = 0; cq < 4; ++cq) {
        int col = cq * 16 + jj;
        float4 v = {0.f, 0.f, 0.f, 0.f};
        if (s >= 0) v = mem4[(size_t)s * 64 + col];
        out4[row * 64 + col] = v;
      }
    }
  }
}

extern "C" void kernel_launch(void* const* d_in, const int* in_sizes, int n_in,
                              void* d_out, int out_size, void* d_ws, size_t ws_size,
                              hipStream_t stream) {
  const float* query = (const float*)d_in[0];
  const float* Bmat = (const float*)d_in[1];
  const float* W1 = (const float*)d_in[2];
  const float* b1 = (const float*)d_in[3];
  const float* W2 = (const float*)d_in[4];
  const float* b2 = (const float*)d_in[5];
  const float* mem = (const float*)d_in[6];
  float* out = (float*)d_out;

  char* ws = (char*)d_ws;
  __hip_bfloat16* ff = (__hip_bfloat16*)ws;                        // 4 MB
  __hip_bfloat16* Mp = (__hip_bfloat16*)(ws + 4194304);            // 512 KB
  __hip_bfloat16* W2p = (__hip_bfloat16*)(ws + 4194304 + 524288);  // 256 KB
  __hip_bfloat16* W1p = (__hip_bfloat16*)(ws + 4194304 + 786432);  // 32 KB

  prep_ff_kernel<<<dim3(2081), dim3(256), 0, stream>>>(W1, b1, W2, mem, query,
                                                       Bmat, W1p, W2p, Mp, ff);
  mega_kernel<<<dim3(512), dim3(256), 0, stream>>>(ff, W1p, W2p, b2, Mp, mem, out);
}